// Round 1
// baseline (336.228 us; speedup 1.0000x reference)
//
#include <hip/hip_runtime.h>
#include <hip/hip_bf16.h>
#include <stdint.h>

typedef __attribute__((ext_vector_type(8))) __bf16 bf16x8;
typedef __attribute__((ext_vector_type(4))) float f32x4;
typedef __attribute__((ext_vector_type(8))) uint16_t u16x8;

__device__ inline uint16_t f2bf(float x) {
  union { float f; uint32_t u; } v; v.f = x;
  uint32_t r = v.u + 0x7fffu + ((v.u >> 16) & 1u);
  return (uint16_t)(r >> 16);
}

#define MFMA16(a, b, c) __builtin_amdgcn_mfma_f32_16x16x32_bf16(a, b, c, 0, 0, 0)
#define GLOAD16(g, l) __builtin_amdgcn_global_load_lds((const __attribute__((address_space(1))) void*)(g), (__attribute__((address_space(3))) void*)(l), 16, 0, 0)

// ---------------- cast f32 -> bf16 (optionally scaled) ----------------
__global__ void cast_f32_bf16(const float* __restrict__ in, uint16_t* __restrict__ out,
                              int n, float scale) {
  int i = (blockIdx.x * 256 + threadIdx.x) * 4;
  if (i >= n) return;
  float4 v = *(const float4*)(in + i);
  ushort4 o;
  o.x = f2bf(v.x * scale); o.y = f2bf(v.y * scale);
  o.z = f2bf(v.z * scale); o.w = f2bf(v.w * scale);
  *(ushort4*)(out + i) = o;
}

// ---------------- GEMM: C[M,N] = A[M,K] * B[N,K]^T  (bf16 in, f32 acc) ----------------
// EPI 0: bf16 out, no bias.  EPI 1: bias + silu, bf16 out.  EPI 2: bias, f32 out.
template <int EPI>
__global__ void gemm_bt(const uint16_t* __restrict__ A, const uint16_t* __restrict__ Bm,
                        void* __restrict__ Cout, const float* __restrict__ bias,
                        int M, int N, int K) {
  __shared__ uint16_t Albs[128 * 64];
  __shared__ uint16_t Blbs[128 * 64];
  const int tid = threadIdx.x;
  const int l = tid & 63, w = tid >> 6;
  const int wr = w >> 1, wc = w & 1;
  const int row0 = blockIdx.x * 128, col0 = blockIdx.y * 128;

  f32x4 acc[4][4] = {};

  const int nk = K >> 6;
  for (int kt = 0; kt < nk; ++kt) {
    __syncthreads();
    const int k0 = kt * 64;
#pragma unroll
    for (int i = 0; i < 4; ++i) {
      const uint16_t* srcA = A + (size_t)(row0 + i * 32 + w * 8 + (l >> 3)) * K + k0 + ((l & 7) * 8);
      GLOAD16(srcA, Albs + (i * 32 + w * 8) * 64);
      const uint16_t* srcB = Bm + (size_t)(col0 + i * 32 + w * 8 + (l >> 3)) * K + k0 + ((l & 7) * 8);
      GLOAD16(srcB, Blbs + (i * 32 + w * 8) * 64);
    }
    __syncthreads();
#pragma unroll
    for (int kk = 0; kk < 2; ++kk) {
      bf16x8 af[4], bfr[4];
#pragma unroll
      for (int m = 0; m < 4; ++m)
        af[m] = *(const bf16x8*)&Albs[(wr * 64 + m * 16 + (l & 15)) * 64 + kk * 32 + ((l >> 4) * 8)];
#pragma unroll
      for (int n = 0; n < 4; ++n)
        bfr[n] = *(const bf16x8*)&Blbs[(wc * 64 + n * 16 + (l & 15)) * 64 + kk * 32 + ((l >> 4) * 8)];
#pragma unroll
      for (int m = 0; m < 4; ++m)
#pragma unroll
        for (int n = 0; n < 4; ++n)
          acc[m][n] = MFMA16(af[m], bfr[n], acc[m][n]);
    }
  }

#pragma unroll
  for (int m = 0; m < 4; ++m)
#pragma unroll
    for (int n = 0; n < 4; ++n)
#pragma unroll
      for (int v = 0; v < 4; ++v) {
        const int r = row0 + wr * 64 + m * 16 + ((l >> 4) << 2) + v;
        const int c = col0 + wc * 64 + n * 16 + (l & 15);
        float x = acc[m][n][v];
        if (EPI == 0) {
          ((uint16_t*)Cout)[(size_t)r * N + c] = f2bf(x);
        } else if (EPI == 1) {
          x += bias[c];
          float s = x / (1.f + __expf(-x));
          ((uint16_t*)Cout)[(size_t)r * N + c] = f2bf(s);
        } else {
          x += bias[c];
          ((float*)Cout)[(size_t)r * N + c] = x;
        }
      }
}

// ---------------- flash attention ----------------
// qkv: [B*S, 3072] bf16 (Q|K|V), Q pre-scaled by 1/8. out: [B*S, 1024] f32.
__global__ __launch_bounds__(256) void attn_kernel(const uint16_t* __restrict__ qkv,
                                                   float* __restrict__ out) {
  __shared__ uint16_t Klds[64 * 64];   // [kv][d], d bytes XOR-swizzled by (kv&7)<<4
  __shared__ uint16_t Vlds[64 * 64];   // V^T [d][kv], kv bytes XOR-swizzled by (d&7)<<4
  __shared__ uint16_t Plds[4][16 * 64];

  const int tid = threadIdx.x;
  const int l = tid & 63, w = tid >> 6;
  const int qt = blockIdx.x;
  const int bh = blockIdx.y;
  const size_t rowbase = (size_t)(bh >> 4) * 2048;
  const int h = bh & 15;
  const int hq = h * 64, hk = 1024 + h * 64, hv = 2048 + h * 64;

  // Q fragments: lane holds Q[row=l&15][k=(l>>4)*8+j]
  bf16x8 qf[2];
  {
    const int qrow = qt * 64 + w * 16 + (l & 15);
    const uint16_t* qp = qkv + (rowbase + qrow) * 3072 + hq + ((l >> 4) * 8);
    qf[0] = *(const bf16x8*)qp;
    qf[1] = *(const bf16x8*)(qp + 32);
  }

  f32x4 O[4] = {};
  float m_run[4], l_run[4];
#pragma unroll
  for (int v = 0; v < 4; ++v) { m_run[v] = -1e30f; l_run[v] = 0.f; }

  for (int kv0 = 0; kv0 < 2048; kv0 += 64) {
    __syncthreads();
    // ---- stage K (global_load_lds, pre-swizzled source) ----
#pragma unroll
    for (int i = 0; i < 2; ++i) {
      const int gcol = 8 * ((l & 7) ^ (l >> 3));  // row&7 == l>>3
      const int r = w * 16 + i * 8 + (l >> 3);
      const uint16_t* src = qkv + (rowbase + kv0 + r) * 3072 + hk + gcol;
      GLOAD16(src, (char*)Klds + w * 2048 + i * 1024);
    }
    // ---- stage V^T (reg-staged, swizzled writes) ----
    {
      const int kv = tid >> 2;
      const int dg = (tid & 3) * 8;
#pragma unroll
      for (int p = 0; p < 2; ++p) {
        const int d0 = dg + p * 32;
        u16x8 vv = *(const u16x8*)(qkv + (rowbase + kv0 + kv) * 3072 + hv + d0);
#pragma unroll
        for (int j = 0; j < 8; ++j)
          Vlds[(((d0 + j) * 64 + kv) ^ (j << 3))] = vv[j];
      }
    }
    __syncthreads();

    // ---- QK^T ----
    f32x4 S[4];
#pragma unroll
    for (int n = 0; n < 4; ++n) {
      f32x4 a = {};
#pragma unroll
      for (int s = 0; s < 2; ++s) {
        const int row = n * 16 + (l & 15);
        const int cq = ((s * 4 + (l >> 4)) ^ (row & 7)) * 8;
        bf16x8 kf = *(const bf16x8*)&Klds[row * 64 + cq];
        a = MFMA16(qf[s], kf, a);
      }
      S[n] = a;
    }

    // ---- online softmax (rows r=(l>>4)*4+v, cols across 16 lanes + 4 n-frags) ----
    float p[4][4];
#pragma unroll
    for (int v = 0; v < 4; ++v) {
      float x = fmaxf(fmaxf(S[0][v], S[1][v]), fmaxf(S[2][v], S[3][v]));
#pragma unroll
      for (int off = 1; off < 16; off <<= 1) x = fmaxf(x, __shfl_xor(x, off, 64));
      const float mn = fmaxf(m_run[v], x);
      const float sc = __expf(m_run[v] - mn);
      m_run[v] = mn;
      float rsum = 0.f;
#pragma unroll
      for (int n = 0; n < 4; ++n) { float e = __expf(S[n][v] - mn); p[n][v] = e; rsum += e; }
#pragma unroll
      for (int off = 1; off < 16; off <<= 1) rsum += __shfl_xor(rsum, off, 64);
      l_run[v] = l_run[v] * sc + rsum;
#pragma unroll
      for (int n = 0; n < 4; ++n) O[n][v] *= sc;
    }

    // ---- P -> LDS (bf16, swizzled) and re-load as A-fragments ----
#pragma unroll
    for (int n = 0; n < 4; ++n)
#pragma unroll
      for (int v = 0; v < 4; ++v) {
        const int r = ((l >> 4) << 2) + v;
        const int c = n * 16 + (l & 15);
        Plds[w][(r * 64 + c) ^ ((r & 7) << 3)] = f2bf(p[n][v]);
      }
    asm volatile("s_waitcnt lgkmcnt(0)" ::: "memory");

    // ---- PV ----
#pragma unroll
    for (int s = 0; s < 2; ++s) {
      const int pr = l & 15;
      const int pc = ((s * 4 + (l >> 4)) ^ (pr & 7)) * 8;
      bf16x8 pf = *(const bf16x8*)&Plds[w][pr * 64 + pc];
#pragma unroll
      for (int n = 0; n < 4; ++n) {
        const int d = n * 16 + (l & 15);
        const int vc = ((s * 4 + (l >> 4)) ^ (d & 7)) * 8;
        bf16x8 vf = *(const bf16x8*)&Vlds[d * 64 + vc];
        O[n] = MFMA16(pf, vf, O[n]);
      }
    }
  }

  // ---- epilogue ----
  float inv[4];
#pragma unroll
  for (int v = 0; v < 4; ++v) inv[v] = 1.f / l_run[v];
#pragma unroll
  for (int n = 0; n < 4; ++n)
#pragma unroll
    for (int v = 0; v < 4; ++v) {
      const int r = qt * 64 + w * 16 + ((l >> 4) << 2) + v;
      const int c = h * 64 + n * 16 + (l & 15);
      out[(rowbase + r) * 1024 + c] = O[n][v] * inv[v];
    }
}

// ---------------- residual + layernorm ----------------
// y = LN(xa + xb) * g + b ; writes f32 (y32) and optionally bf16 (y16)
__global__ __launch_bounds__(256) void ln_kernel(const float* __restrict__ xa,
                                                 const float* __restrict__ xb,
                                                 const float* __restrict__ g,
                                                 const float* __restrict__ b,
                                                 float* __restrict__ y32,
                                                 uint16_t* __restrict__ y16) {
  const int row = blockIdx.x;
  const int t = threadIdx.x;
  const int l = t & 63, w = t >> 6;
  float4 va = *((const float4*)(xa + (size_t)row * 1024) + t);
  float4 vb = *((const float4*)(xb + (size_t)row * 1024) + t);
  const float x0 = va.x + vb.x, x1 = va.y + vb.y, x2 = va.z + vb.z, x3 = va.w + vb.w;
  float s = x0 + x1 + x2 + x3;
  float q = x0 * x0 + x1 * x1 + x2 * x2 + x3 * x3;
#pragma unroll
  for (int off = 1; off < 64; off <<= 1) {
    s += __shfl_xor(s, off, 64);
    q += __shfl_xor(q, off, 64);
  }
  __shared__ float red[8];
  if (l == 0) { red[w] = s; red[w + 4] = q; }
  __syncthreads();
  s = red[0] + red[1] + red[2] + red[3];
  q = red[4] + red[5] + red[6] + red[7];
  const float mu = s * (1.f / 1024.f);
  const float var = q * (1.f / 1024.f) - mu * mu;
  const float rstd = rsqrtf(var + 1e-5f);
  float4 vg = *((const float4*)g + t);
  float4 vbb = *((const float4*)b + t);
  float y0 = (x0 - mu) * rstd * vg.x + vbb.x;
  float y1 = (x1 - mu) * rstd * vg.y + vbb.y;
  float y2 = (x2 - mu) * rstd * vg.z + vbb.z;
  float y3 = (x3 - mu) * rstd * vg.w + vbb.w;
  *((float4*)(y32 + (size_t)row * 1024) + t) = make_float4(y0, y1, y2, y3);
  if (y16) {
    union { uint16_t u[4]; uint64_t v; } o;
    o.u[0] = f2bf(y0); o.u[1] = f2bf(y1); o.u[2] = f2bf(y2); o.u[3] = f2bf(y3);
    *((uint64_t*)(y16 + (size_t)row * 1024) + t) = o.v;
  }
}

extern "C" void kernel_launch(void* const* d_in, const int* in_sizes, int n_in,
                              void* d_out, int out_size, void* d_ws, size_t ws_size,
                              hipStream_t stream) {
  const float* embed = (const float*)d_in[0];
  const float* Wk = (const float*)d_in[1];
  const float* Wq = (const float*)d_in[2];
  const float* Wv = (const float*)d_in[3];
  const float* w1w = (const float*)d_in[4];
  const float* w1bias = (const float*)d_in[5];
  const float* w2w = (const float*)d_in[6];
  const float* w2bias = (const float*)d_in[7];
  const float* lng = (const float*)d_in[8];
  const float* lnb = (const float*)d_in[9];
  const float* ln2g = (const float*)d_in[10];
  const float* ln2b = (const float*)d_in[11];

  char* ws = (char*)d_ws;
  uint16_t* qkv  = (uint16_t*)(ws);                  // 4096*3072*2 = 25165824
  uint16_t* xbf  = (uint16_t*)(ws + 25165824);       // embed_bf16, later y_bf16 (8388608)
  uint16_t* wqkv = (uint16_t*)(ws + 33554432);       // 6291456
  uint16_t* w1b  = (uint16_t*)(ws + 39845888);       // 8388608
  uint16_t* w2b  = (uint16_t*)(ws + 48234496);       // 8388608
  float*    attf = (float*)(ws + 56623104);          // attn out f32, later out2 f32 (16777216)
  float*    yf   = (float*)(ws + 73400320);          // 16777216
  uint16_t* hid  = (uint16_t*)(ws + 90177536);       // 33554432

  auto cast = [&](const float* in, uint16_t* outp, int n, float sc) {
    cast_f32_bf16<<<dim3((n / 4 + 255) / 256), dim3(256), 0, stream>>>(in, outp, n, sc);
  };
  cast(embed, xbf, 4194304, 1.f);
  cast(Wq, wqkv, 1048576, 0.125f);  // fold 1/sqrt(64) into Q
  cast(Wk, wqkv + 1048576, 1048576, 1.f);
  cast(Wv, wqkv + 2097152, 1048576, 1.f);
  cast(w1w, w1b, 4194304, 1.f);
  cast(w2w, w2b, 4194304, 1.f);

  // QKV projection: [4096,1024] x [3072,1024]^T -> [4096,3072] bf16
  gemm_bt<0><<<dim3(32, 24), dim3(256), 0, stream>>>(xbf, wqkv, qkv, nullptr, 4096, 3072, 1024);
  // attention
  attn_kernel<<<dim3(32, 32), dim3(256), 0, stream>>>(qkv, attf);
  // residual + LN1 -> yf (f32), xbf (bf16)
  ln_kernel<<<dim3(4096), dim3(256), 0, stream>>>(attf, embed, lng, lnb, yf, xbf);
  // FFN1: silu(y @ w1^T + b1) -> hid bf16
  gemm_bt<1><<<dim3(32, 32), dim3(256), 0, stream>>>(xbf, w1b, hid, w1bias, 4096, 4096, 1024);
  // FFN2: hid @ w2^T + b2 -> attf f32 (reuse)
  gemm_bt<2><<<dim3(32, 8), dim3(256), 0, stream>>>(hid, w2b, attf, w2bias, 4096, 1024, 4096);
  // residual + LN2 -> d_out
  ln_kernel<<<dim3(4096), dim3(256), 0, stream>>>(attf, yf, ln2g, ln2b, (float*)d_out, nullptr);
}

// Round 2
// 260.337 us; speedup vs baseline: 1.2915x; 1.2915x over previous
//
#include <hip/hip_runtime.h>
#include <hip/hip_bf16.h>
#include <stdint.h>

typedef __attribute__((ext_vector_type(8))) __bf16 bf16x8;
typedef __attribute__((ext_vector_type(4))) float f32x4;
typedef __attribute__((ext_vector_type(16))) float f32x16;
typedef __attribute__((ext_vector_type(8))) uint16_t u16x8;

__device__ inline uint16_t f2bf(float x) {
  union { float f; uint32_t u; } v; v.f = x;
  uint32_t r = v.u + 0x7fffu + ((v.u >> 16) & 1u);
  return (uint16_t)(r >> 16);
}

#define MFMA16(a, b, c) __builtin_amdgcn_mfma_f32_16x16x32_bf16(a, b, c, 0, 0, 0)
#define MFMA32(a, b, c) __builtin_amdgcn_mfma_f32_32x32x16_bf16(a, b, c, 0, 0, 0)
#define GLOAD16(g, l) __builtin_amdgcn_global_load_lds((const __attribute__((address_space(1))) void*)(g), (__attribute__((address_space(3))) void*)(l), 16, 0, 0)

#if __has_builtin(__builtin_amdgcn_exp2f)
#define EXP2(x) __builtin_amdgcn_exp2f(x)
#else
#define EXP2(x) exp2f(x)
#endif

__device__ inline uint32_t cvtpk_bf16(float lo, float hi) {
  uint32_t r;
  asm("v_cvt_pk_bf16_f32 %0, %1, %2" : "=v"(r) : "v"(lo), "v"(hi));
  return r;
}
__device__ inline void perm32swap(uint32_t& a, uint32_t& b) {
  asm volatile("v_permlane32_swap_b32 %0, %1" : "+v"(a), "+v"(b));
}

// ---------------- cast f32 -> bf16 (optionally scaled) ----------------
__global__ void cast_f32_bf16(const float* __restrict__ in, uint16_t* __restrict__ out,
                              int n, float scale) {
  int i = (blockIdx.x * 256 + threadIdx.x) * 4;
  if (i >= n) return;
  float4 v = *(const float4*)(in + i);
  ushort4 o;
  o.x = f2bf(v.x * scale); o.y = f2bf(v.y * scale);
  o.z = f2bf(v.z * scale); o.w = f2bf(v.w * scale);
  *(ushort4*)(out + i) = o;
}

// ---------------- GEMM: C[M,N] = A[M,K] * B[N,K]^T  (bf16 in, f32 acc) ----------------
template <int EPI>
__global__ void gemm_bt(const uint16_t* __restrict__ A, const uint16_t* __restrict__ Bm,
                        void* __restrict__ Cout, const float* __restrict__ bias,
                        int M, int N, int K) {
  __shared__ uint16_t Albs[128 * 64];
  __shared__ uint16_t Blbs[128 * 64];
  const int tid = threadIdx.x;
  const int l = tid & 63, w = tid >> 6;
  const int wr = w >> 1, wc = w & 1;
  const int row0 = blockIdx.x * 128, col0 = blockIdx.y * 128;

  f32x4 acc[4][4] = {};

  const int nk = K >> 6;
  for (int kt = 0; kt < nk; ++kt) {
    __syncthreads();
    const int k0 = kt * 64;
#pragma unroll
    for (int i = 0; i < 4; ++i) {
      const uint16_t* srcA = A + (size_t)(row0 + i * 32 + w * 8 + (l >> 3)) * K + k0 + ((l & 7) * 8);
      GLOAD16(srcA, Albs + (i * 32 + w * 8) * 64);
      const uint16_t* srcB = Bm + (size_t)(col0 + i * 32 + w * 8 + (l >> 3)) * K + k0 + ((l & 7) * 8);
      GLOAD16(srcB, Blbs + (i * 32 + w * 8) * 64);
    }
    __syncthreads();
#pragma unroll
    for (int kk = 0; kk < 2; ++kk) {
      bf16x8 af[4], bfr[4];
#pragma unroll
      for (int m = 0; m < 4; ++m)
        af[m] = *(const bf16x8*)&Albs[(wr * 64 + m * 16 + (l & 15)) * 64 + kk * 32 + ((l >> 4) * 8)];
#pragma unroll
      for (int n = 0; n < 4; ++n)
        bfr[n] = *(const bf16x8*)&Blbs[(wc * 64 + n * 16 + (l & 15)) * 64 + kk * 32 + ((l >> 4) * 8)];
#pragma unroll
      for (int m = 0; m < 4; ++m)
#pragma unroll
        for (int n = 0; n < 4; ++n)
          acc[m][n] = MFMA16(af[m], bfr[n], acc[m][n]);
    }
  }

#pragma unroll
  for (int m = 0; m < 4; ++m)
#pragma unroll
    for (int n = 0; n < 4; ++n)
#pragma unroll
      for (int v = 0; v < 4; ++v) {
        const int r = row0 + wr * 64 + m * 16 + ((l >> 4) << 2) + v;
        const int c = col0 + wc * 64 + n * 16 + (l & 15);
        float x = acc[m][n][v];
        if (EPI == 0) {
          ((uint16_t*)Cout)[(size_t)r * N + c] = f2bf(x);
        } else if (EPI == 1) {
          x += bias[c];
          float s = x / (1.f + __expf(-x));
          ((uint16_t*)Cout)[(size_t)r * N + c] = f2bf(s);
        } else {
          x += bias[c];
          ((float*)Cout)[(size_t)r * N + c] = x;
        }
      }
}

// ---------------- V transpose: qkv V slice -> Vt[bh][64 d][2048 s] ----------------
__global__ __launch_bounds__(256) void transpose_v(const uint16_t* __restrict__ qkv,
                                                   uint16_t* __restrict__ Vt) {
  __shared__ uint16_t t[64][72];
  const int kv0 = blockIdx.x * 64;
  const int bh = blockIdx.y;
  const size_t rowbase = (size_t)(bh >> 4) * 2048;
  const int hv = 2048 + (bh & 15) * 64;
  const int tid = threadIdx.x;
  const int r = tid >> 3, c8 = (tid & 7) * 8;
#pragma unroll
  for (int i = 0; i < 2; ++i) {
    const int row = i * 32 + r;
    u16x8 v = *(const u16x8*)(qkv + (rowbase + kv0 + row) * 3072 + hv + c8);
#pragma unroll
    for (int j = 0; j < 8; ++j) t[c8 + j][row] = v[j];
  }
  __syncthreads();
#pragma unroll
  for (int i = 0; i < 2; ++i) {
    const int d = i * 32 + r;
    u16x8 o;
#pragma unroll
    for (int j = 0; j < 8; ++j) o[j] = t[d][c8 + j];
    *(u16x8*)(Vt + ((size_t)bh * 64 + d) * 2048 + kv0 + c8) = o;
  }
}

// ---------------- flash attention (swapped QK^T, 32x32 MFMA) ----------------
// qkv: [B*S,3072] bf16, Q pre-scaled by 0.125*log2e. Vt: [32][64][2048] bf16.
// out: [B*S,1024] f32. Per wave: 32 q-rows; block: 4 waves = 128 q-rows.
__global__ __launch_bounds__(256, 2) void attn_kernel(const uint16_t* __restrict__ qkv,
                                                      const uint16_t* __restrict__ Vt,
                                                      float* __restrict__ out) {
  __shared__ uint16_t Klds[2][4096];  // [64 kv][64 d] swizzled
  __shared__ uint16_t Vlds[2][4096];  // [64 d][64 kv] swizzled
  const int tid = threadIdx.x;
  const int l = tid & 63, w = tid >> 6;
  const int lq = l & 31, hi = l >> 5;
  const int qt = blockIdx.x, bh = blockIdx.y;
  const size_t rowbase = (size_t)(bh >> 4) * 2048;
  const int h = bh & 15;
  const int hq = h * 64, hk = 1024 + h * 64;

  // Q fragments (B-operand): lane holds Q[qrow][c*16 + hi*8 + j]
  const int qrow = qt * 128 + w * 32 + lq;
  bf16x8 qf[4];
  {
    const uint16_t* qp = qkv + (rowbase + qrow) * 3072 + hq + hi * 8;
#pragma unroll
    for (int c = 0; c < 4; ++c) qf[c] = *(const bf16x8*)(qp + c * 16);
  }

  // staging geometry: lane covers row = pass*32 + w*8 + (l>>3), pre-swizzled col
  const int srow = w * 8 + (l >> 3);
  const int gcol = 8 * ((l & 7) ^ (l >> 3));

  f32x16 ot[2];
#pragma unroll
  for (int r = 0; r < 16; ++r) { ot[0][r] = 0.f; ot[1][r] = 0.f; }
  float m_run = -1e30f, l_run = 0.f;

  auto STAGE = [&](int buf, int kv0) {
#pragma unroll
    for (int p = 0; p < 2; ++p) {
      const uint16_t* srcK = qkv + (rowbase + kv0 + p * 32 + srow) * 3072 + hk + gcol;
      GLOAD16(srcK, (char*)&Klds[buf][0] + p * 4096 + w * 1024);
      const uint16_t* srcV = Vt + ((size_t)bh * 64 + p * 32 + srow) * 2048 + kv0 + gcol;
      GLOAD16(srcV, (char*)&Vlds[buf][0] + p * 4096 + w * 1024);
    }
  };

  STAGE(0, 0);
  int cur = 0;
  const int swz = (lq & 7) << 4;

  for (int t = 0; t < 32; ++t) {
    asm volatile("s_waitcnt vmcnt(0)" ::: "memory");
    __builtin_amdgcn_s_barrier();
    if (t < 31) STAGE(cur ^ 1, (t + 1) * 64);

    // ---- QK^T: S^T[kv][q] ----
    f32x16 st[2];
#pragma unroll
    for (int b = 0; b < 2; ++b) {
      f32x16 a;
#pragma unroll
      for (int r = 0; r < 16; ++r) a[r] = 0.f;
      __builtin_amdgcn_s_setprio(1);
#pragma unroll
      for (int c = 0; c < 4; ++c) {
        const int cb = (c * 32 + hi * 16) ^ swz;
        bf16x8 kf = *(const bf16x8*)((const char*)&Klds[cur][0] + (b * 32 + lq) * 128 + cb);
        a = MFMA32(kf, qf[c], a);
      }
      __builtin_amdgcn_s_setprio(0);
      st[b] = a;
    }

    // ---- online softmax in log2 space; lane owns kv = 32b + (r&3)+4hi+8(r>>2), q = lq ----
    float mloc = st[0][0];
#pragma unroll
    for (int r = 1; r < 16; ++r) mloc = fmaxf(mloc, st[0][r]);
#pragma unroll
    for (int r = 0; r < 16; ++r) mloc = fmaxf(mloc, st[1][r]);
    const float mtile = fmaxf(mloc, __shfl_xor(mloc, 32, 64));
    if (!__all(mtile <= m_run + 8.f)) {
      const float mnew = fmaxf(m_run, mtile);
      const float sc = EXP2(m_run - mnew);
      m_run = mnew;
      l_run *= sc;
#pragma unroll
      for (int r = 0; r < 16; ++r) { ot[0][r] *= sc; ot[1][r] *= sc; }
    }
    float p0[16], p1[16];
    float rsum = 0.f;
#pragma unroll
    for (int r = 0; r < 16; ++r) { p0[r] = EXP2(st[0][r] - m_run); rsum += p0[r]; }
#pragma unroll
    for (int r = 0; r < 16; ++r) { p1[r] = EXP2(st[1][r] - m_run); rsum += p1[r]; }
    l_run += rsum + __shfl_xor(rsum, 32, 64);

    // ---- P -> A-fragment redistribution (cvt_pk + permlane32_swap) ----
    uint32_t pa[4][4];
#pragma unroll
    for (int b = 0; b < 2; ++b) {
      const float* pp = b ? p1 : p0;
#pragma unroll
      for (int c = 0; c < 2; ++c) {
        uint32_t a0 = cvtpk_bf16(pp[8 * c + 0], pp[8 * c + 1]);
        uint32_t a1 = cvtpk_bf16(pp[8 * c + 2], pp[8 * c + 3]);
        uint32_t b0 = cvtpk_bf16(pp[8 * c + 4], pp[8 * c + 5]);
        uint32_t b1 = cvtpk_bf16(pp[8 * c + 6], pp[8 * c + 7]);
        perm32swap(a0, b0);
        perm32swap(a1, b1);
        pa[b * 2 + c][0] = a0; pa[b * 2 + c][1] = a1;
        pa[b * 2 + c][2] = b0; pa[b * 2 + c][3] = b1;
      }
    }

    // ---- PV: O^T[d][q] += Vt-frag * P-frag ----
    __builtin_amdgcn_s_setprio(1);
#pragma unroll
    for (int ks = 0; ks < 4; ++ks) {
      bf16x8 pf = *(bf16x8*)&pa[ks][0];
#pragma unroll
      for (int db = 0; db < 2; ++db) {
        const int cb = (ks * 32 + hi * 16) ^ swz;
        bf16x8 vf = *(const bf16x8*)((const char*)&Vlds[cur][0] + (db * 32 + lq) * 128 + cb);
        ot[db] = MFMA32(vf, pf, ot[db]);
      }
    }
    __builtin_amdgcn_s_setprio(0);
    cur ^= 1;
  }

  // ---- epilogue: d = 32db + (r&3) + 4hi + 8(r>>2), q = lq ----
  const float linv = 1.f / l_run;
  float* orow = out + (rowbase + qrow) * 1024 + h * 64;
#pragma unroll
  for (int db = 0; db < 2; ++db)
#pragma unroll
    for (int m = 0; m < 4; ++m) {
      float4 v;
      v.x = ot[db][4 * m + 0] * linv;
      v.y = ot[db][4 * m + 1] * linv;
      v.z = ot[db][4 * m + 2] * linv;
      v.w = ot[db][4 * m + 3] * linv;
      *(float4*)(orow + db * 32 + 8 * m + 4 * hi) = v;
    }
}

// ---------------- residual + layernorm ----------------
__global__ __launch_bounds__(256) void ln_kernel(const float* __restrict__ xa,
                                                 const float* __restrict__ xb,
                                                 const float* __restrict__ g,
                                                 const float* __restrict__ b,
                                                 float* __restrict__ y32,
                                                 uint16_t* __restrict__ y16) {
  const int row = blockIdx.x;
  const int t = threadIdx.x;
  const int l = t & 63, w = t >> 6;
  float4 va = *((const float4*)(xa + (size_t)row * 1024) + t);
  float4 vb = *((const float4*)(xb + (size_t)row * 1024) + t);
  const float x0 = va.x + vb.x, x1 = va.y + vb.y, x2 = va.z + vb.z, x3 = va.w + vb.w;
  float s = x0 + x1 + x2 + x3;
  float q = x0 * x0 + x1 * x1 + x2 * x2 + x3 * x3;
#pragma unroll
  for (int off = 1; off < 64; off <<= 1) {
    s += __shfl_xor(s, off, 64);
    q += __shfl_xor(q, off, 64);
  }
  __shared__ float red[8];
  if (l == 0) { red[w] = s; red[w + 4] = q; }
  __syncthreads();
  s = red[0] + red[1] + red[2] + red[3];
  q = red[4] + red[5] + red[6] + red[7];
  const float mu = s * (1.f / 1024.f);
  const float var = q * (1.f / 1024.f) - mu * mu;
  const float rstd = rsqrtf(var + 1e-5f);
  float4 vg = *((const float4*)g + t);
  float4 vbb = *((const float4*)b + t);
  float y0 = (x0 - mu) * rstd * vg.x + vbb.x;
  float y1 = (x1 - mu) * rstd * vg.y + vbb.y;
  float y2 = (x2 - mu) * rstd * vg.z + vbb.z;
  float y3 = (x3 - mu) * rstd * vg.w + vbb.w;
  *((float4*)(y32 + (size_t)row * 1024) + t) = make_float4(y0, y1, y2, y3);
  if (y16) {
    union { uint16_t u[4]; uint64_t v; } o;
    o.u[0] = f2bf(y0); o.u[1] = f2bf(y1); o.u[2] = f2bf(y2); o.u[3] = f2bf(y3);
    *((uint64_t*)(y16 + (size_t)row * 1024) + t) = o.v;
  }
}

extern "C" void kernel_launch(void* const* d_in, const int* in_sizes, int n_in,
                              void* d_out, int out_size, void* d_ws, size_t ws_size,
                              hipStream_t stream) {
  const float* embed = (const float*)d_in[0];
  const float* Wk = (const float*)d_in[1];
  const float* Wq = (const float*)d_in[2];
  const float* Wv = (const float*)d_in[3];
  const float* w1w = (const float*)d_in[4];
  const float* w1bias = (const float*)d_in[5];
  const float* w2w = (const float*)d_in[6];
  const float* w2bias = (const float*)d_in[7];
  const float* lng = (const float*)d_in[8];
  const float* lnb = (const float*)d_in[9];
  const float* ln2g = (const float*)d_in[10];
  const float* ln2b = (const float*)d_in[11];

  char* ws = (char*)d_ws;
  uint16_t* qkv  = (uint16_t*)(ws);                  // 25165824
  uint16_t* xbf  = (uint16_t*)(ws + 25165824);       // 8388608
  uint16_t* wqkv = (uint16_t*)(ws + 33554432);       // 6291456
  uint16_t* w1b  = (uint16_t*)(ws + 39845888);       // 8388608
  uint16_t* w2b  = (uint16_t*)(ws + 48234496);       // 8388608
  float*    attf = (float*)(ws + 56623104);          // 16777216
  float*    yf   = (float*)(ws + 73400320);          // 16777216
  uint16_t* hid  = (uint16_t*)(ws + 90177536);       // 33554432 (FFN1 out)
  uint16_t* Vt   = (uint16_t*)(ws + 90177536);       // 8388608 (only live pre-FFN1)

  auto cast = [&](const float* in, uint16_t* outp, int n, float sc) {
    cast_f32_bf16<<<dim3((n / 4 + 255) / 256), dim3(256), 0, stream>>>(in, outp, n, sc);
  };
  cast(embed, xbf, 4194304, 1.f);
  cast(Wq, wqkv, 1048576, 0.125f * 1.44269504f);  // fold 1/sqrt(64) and log2(e) into Q
  cast(Wk, wqkv + 1048576, 1048576, 1.f);
  cast(Wv, wqkv + 2097152, 1048576, 1.f);
  cast(w1w, w1b, 4194304, 1.f);
  cast(w2w, w2b, 4194304, 1.f);

  // QKV projection
  gemm_bt<0><<<dim3(32, 24), dim3(256), 0, stream>>>(xbf, wqkv, qkv, nullptr, 4096, 3072, 1024);
  // V transpose
  transpose_v<<<dim3(32, 32), dim3(256), 0, stream>>>(qkv, Vt);
  // attention
  attn_kernel<<<dim3(16, 32), dim3(256), 0, stream>>>(qkv, Vt, attf);
  // residual + LN1
  ln_kernel<<<dim3(4096), dim3(256), 0, stream>>>(attf, embed, lng, lnb, yf, xbf);
  // FFN1
  gemm_bt<1><<<dim3(32, 32), dim3(256), 0, stream>>>(xbf, w1b, hid, w1bias, 4096, 4096, 1024);
  // FFN2
  gemm_bt<2><<<dim3(32, 8), dim3(256), 0, stream>>>(hid, w2b, attf, w2bias, 4096, 1024, 4096);
  // residual + LN2
  ln_kernel<<<dim3(4096), dim3(256), 0, stream>>>(attf, yf, ln2g, ln2b, (float*)d_out, nullptr);
}

// Round 3
// 234.184 us; speedup vs baseline: 1.4357x; 1.1117x over previous
//
#include <hip/hip_runtime.h>
#include <hip/hip_bf16.h>
#include <stdint.h>

typedef __attribute__((ext_vector_type(8))) __bf16 bf16x8;
typedef __attribute__((ext_vector_type(4))) float f32x4;
typedef __attribute__((ext_vector_type(16))) float f32x16;
typedef __attribute__((ext_vector_type(8))) uint16_t u16x8;

__device__ inline uint16_t f2bf(float x) {
  union { float f; uint32_t u; } v; v.f = x;
  uint32_t r = v.u + 0x7fffu + ((v.u >> 16) & 1u);
  return (uint16_t)(r >> 16);
}

#define MFMA16(a, b, c) __builtin_amdgcn_mfma_f32_16x16x32_bf16(a, b, c, 0, 0, 0)
#define MFMA32(a, b, c) __builtin_amdgcn_mfma_f32_32x32x16_bf16(a, b, c, 0, 0, 0)
#define GLOAD16(g, l) __builtin_amdgcn_global_load_lds((const __attribute__((address_space(1))) void*)(g), (__attribute__((address_space(3))) void*)(l), 16, 0, 0)

#if __has_builtin(__builtin_amdgcn_exp2f)
#define EXP2(x) __builtin_amdgcn_exp2f(x)
#else
#define EXP2(x) exp2f(x)
#endif

__device__ inline uint32_t cvtpk_bf16(float lo, float hi) {
  uint32_t r;
  asm("v_cvt_pk_bf16_f32 %0, %1, %2" : "=v"(r) : "v"(lo), "v"(hi));
  return r;
}
__device__ inline void perm32swap(uint32_t& a, uint32_t& b) {
  asm volatile("v_permlane32_swap_b32 %0, %1" : "+v"(a), "+v"(b));
}

// ---------------- fused cast f32 -> bf16, all tensors, static segment map ----------------
// segments (element idx): [0,4M) embed  [4M,5M) Wq*scale  [5M,6M) Wk  [6M,7M) Wv
//                         [7M,11M) w1   [11M,15M) w2      total 15728640
__global__ void cast_all(const float* __restrict__ embed, const float* __restrict__ Wq,
                         const float* __restrict__ Wk, const float* __restrict__ Wv,
                         const float* __restrict__ w1w, const float* __restrict__ w2w,
                         uint16_t* __restrict__ xbf, uint16_t* __restrict__ wqkv,
                         uint16_t* __restrict__ w1b, uint16_t* __restrict__ w2b) {
  const int i = (blockIdx.x * 256 + threadIdx.x) * 4;
  const float* src; uint16_t* dst; float sc = 1.f; int off;
  if (i < 4194304)       { src = embed; dst = xbf;            off = i; }
  else if (i < 5242880)  { src = Wq;  dst = wqkv;             off = i - 4194304; sc = 0.125f * 1.44269504f; }
  else if (i < 6291456)  { src = Wk;  dst = wqkv + 1048576;   off = i - 5242880; }
  else if (i < 7340032)  { src = Wv;  dst = wqkv + 2097152;   off = i - 6291456; }
  else if (i < 11534336) { src = w1w; dst = w1b;              off = i - 7340032; }
  else                   { src = w2w; dst = w2b;              off = i - 11534336; }
  float4 v = *(const float4*)(src + off);
  ushort4 o;
  o.x = f2bf(v.x * sc); o.y = f2bf(v.y * sc);
  o.z = f2bf(v.z * sc); o.w = f2bf(v.w * sc);
  *(ushort4*)(dst + off) = o;
}

// ---------------- GEMM: C[M,N] = A[M,K] * B[N,K]^T  (bf16 in, f32 acc) ----------------
// K = per-slice loop extent, ldk = row stride of A and B (elements).
// blockIdx.z selects split-K slice: slice kz reads A/B at column offset kz*K and
// writes Cout (kz==0, with bias) or Cout2 (kz==1, no bias).
// EPI 0: bf16 out, no bias.  EPI 1: bias + silu, bf16 out.  EPI 2: bias, f32 out.
template <int EPI>
__global__ void gemm_bt(const uint16_t* __restrict__ A, const uint16_t* __restrict__ Bm,
                        void* __restrict__ Cout, void* __restrict__ Cout2,
                        const float* __restrict__ bias, int M, int N, int K, int ldk) {
  __shared__ uint16_t Albs[128 * 64];
  __shared__ uint16_t Blbs[128 * 64];
  const int tid = threadIdx.x;
  const int l = tid & 63, w = tid >> 6;
  const int wr = w >> 1, wc = w & 1;

  // XCD-aware bijective swizzle (grids here always have gx*gy % 8 == 0)
  const int gx = gridDim.x;
  const int nwg = gx * gridDim.y;
  const int orig = blockIdx.y * gx + blockIdx.x;
  const int wg = (orig & 7) * (nwg >> 3) + (orig >> 3);
  const int row0 = (wg % gx) * 128;
  const int col0 = (wg / gx) * 128;

  const int kz = blockIdx.z;
  A += (size_t)kz * K;
  Bm += (size_t)kz * K;
  void* Co = kz ? Cout2 : Cout;
  const float* bp = kz ? (const float*)nullptr : bias;

  f32x4 acc[4][4] = {};

  const int nk = K >> 6;
  for (int kt = 0; kt < nk; ++kt) {
    __syncthreads();
    const int k0 = kt * 64;
#pragma unroll
    for (int i = 0; i < 4; ++i) {
      const uint16_t* srcA = A + (size_t)(row0 + i * 32 + w * 8 + (l >> 3)) * ldk + k0 + ((l & 7) * 8);
      GLOAD16(srcA, Albs + (i * 32 + w * 8) * 64);
      const uint16_t* srcB = Bm + (size_t)(col0 + i * 32 + w * 8 + (l >> 3)) * ldk + k0 + ((l & 7) * 8);
      GLOAD16(srcB, Blbs + (i * 32 + w * 8) * 64);
    }
    __syncthreads();
#pragma unroll
    for (int kk = 0; kk < 2; ++kk) {
      bf16x8 af[4], bfr[4];
#pragma unroll
      for (int m = 0; m < 4; ++m)
        af[m] = *(const bf16x8*)&Albs[(wr * 64 + m * 16 + (l & 15)) * 64 + kk * 32 + ((l >> 4) * 8)];
#pragma unroll
      for (int n = 0; n < 4; ++n)
        bfr[n] = *(const bf16x8*)&Blbs[(wc * 64 + n * 16 + (l & 15)) * 64 + kk * 32 + ((l >> 4) * 8)];
#pragma unroll
      for (int m = 0; m < 4; ++m)
#pragma unroll
        for (int n = 0; n < 4; ++n)
          acc[m][n] = MFMA16(af[m], bfr[n], acc[m][n]);
    }
  }

#pragma unroll
  for (int m = 0; m < 4; ++m)
#pragma unroll
    for (int n = 0; n < 4; ++n)
#pragma unroll
      for (int v = 0; v < 4; ++v) {
        const int r = row0 + wr * 64 + m * 16 + ((l >> 4) << 2) + v;
        const int c = col0 + wc * 64 + n * 16 + (l & 15);
        float x = acc[m][n][v];
        if (EPI == 0) {
          ((uint16_t*)Co)[(size_t)r * N + c] = f2bf(x);
        } else if (EPI == 1) {
          x += bp[c];
          float s = x / (1.f + __expf(-x));
          ((uint16_t*)Co)[(size_t)r * N + c] = f2bf(s);
        } else {
          if (bp) x += bp[c];
          ((float*)Co)[(size_t)r * N + c] = x;
        }
      }
}

// ---------------- V transpose: qkv V slice -> Vt[bh][64 d][2048 s] ----------------
__global__ __launch_bounds__(256) void transpose_v(const uint16_t* __restrict__ qkv,
                                                   uint16_t* __restrict__ Vt) {
  __shared__ uint16_t t[64][72];
  const int kv0 = blockIdx.x * 64;
  const int bh = blockIdx.y;
  const size_t rowbase = (size_t)(bh >> 4) * 2048;
  const int hv = 2048 + (bh & 15) * 64;
  const int tid = threadIdx.x;
  const int r = tid >> 3, c8 = (tid & 7) * 8;
#pragma unroll
  for (int i = 0; i < 2; ++i) {
    const int row = i * 32 + r;
    u16x8 v = *(const u16x8*)(qkv + (rowbase + kv0 + row) * 3072 + hv + c8);
#pragma unroll
    for (int j = 0; j < 8; ++j) t[c8 + j][row] = v[j];
  }
  __syncthreads();
#pragma unroll
  for (int i = 0; i < 2; ++i) {
    const int d = i * 32 + r;
    u16x8 o;
#pragma unroll
    for (int j = 0; j < 8; ++j) o[j] = t[d][c8 + j];
    *(u16x8*)(Vt + ((size_t)bh * 64 + d) * 2048 + kv0 + c8) = o;
  }
}

// ---------------- flash attention (swapped QK^T, 32x32 MFMA) ----------------
__global__ __launch_bounds__(256, 2) void attn_kernel(const uint16_t* __restrict__ qkv,
                                                      const uint16_t* __restrict__ Vt,
                                                      float* __restrict__ out) {
  __shared__ uint16_t Klds[2][4096];  // [64 kv][64 d] swizzled
  __shared__ uint16_t Vlds[2][4096];  // [64 d][64 kv] swizzled
  const int tid = threadIdx.x;
  const int l = tid & 63, w = tid >> 6;
  const int lq = l & 31, hi = l >> 5;
  const int qt = blockIdx.x, bh = blockIdx.y;
  const size_t rowbase = (size_t)(bh >> 4) * 2048;
  const int h = bh & 15;
  const int hq = h * 64, hk = 1024 + h * 64;

  const int qrow = qt * 128 + w * 32 + lq;
  bf16x8 qf[4];
  {
    const uint16_t* qp = qkv + (rowbase + qrow) * 3072 + hq + hi * 8;
#pragma unroll
    for (int c = 0; c < 4; ++c) qf[c] = *(const bf16x8*)(qp + c * 16);
  }

  const int srow = w * 8 + (l >> 3);
  const int gcol = 8 * ((l & 7) ^ (l >> 3));

  f32x16 ot[2];
#pragma unroll
  for (int r = 0; r < 16; ++r) { ot[0][r] = 0.f; ot[1][r] = 0.f; }
  float m_run = -1e30f, l_run = 0.f;

  auto STAGE = [&](int buf, int kv0) {
#pragma unroll
    for (int p = 0; p < 2; ++p) {
      const uint16_t* srcK = qkv + (rowbase + kv0 + p * 32 + srow) * 3072 + hk + gcol;
      GLOAD16(srcK, (char*)&Klds[buf][0] + p * 4096 + w * 1024);
      const uint16_t* srcV = Vt + ((size_t)bh * 64 + p * 32 + srow) * 2048 + kv0 + gcol;
      GLOAD16(srcV, (char*)&Vlds[buf][0] + p * 4096 + w * 1024);
    }
  };

  STAGE(0, 0);
  int cur = 0;
  const int swz = (lq & 7) << 4;

  for (int t = 0; t < 32; ++t) {
    asm volatile("s_waitcnt vmcnt(0)" ::: "memory");
    __builtin_amdgcn_s_barrier();
    if (t < 31) STAGE(cur ^ 1, (t + 1) * 64);

    f32x16 st[2];
#pragma unroll
    for (int b = 0; b < 2; ++b) {
      f32x16 a;
#pragma unroll
      for (int r = 0; r < 16; ++r) a[r] = 0.f;
      __builtin_amdgcn_s_setprio(1);
#pragma unroll
      for (int c = 0; c < 4; ++c) {
        const int cb = (c * 32 + hi * 16) ^ swz;
        bf16x8 kf = *(const bf16x8*)((const char*)&Klds[cur][0] + (b * 32 + lq) * 128 + cb);
        a = MFMA32(kf, qf[c], a);
      }
      __builtin_amdgcn_s_setprio(0);
      st[b] = a;
    }

    float mloc = st[0][0];
#pragma unroll
    for (int r = 1; r < 16; ++r) mloc = fmaxf(mloc, st[0][r]);
#pragma unroll
    for (int r = 0; r < 16; ++r) mloc = fmaxf(mloc, st[1][r]);
    const float mtile = fmaxf(mloc, __shfl_xor(mloc, 32, 64));
    if (!__all(mtile <= m_run + 8.f)) {
      const float mnew = fmaxf(m_run, mtile);
      const float sc = EXP2(m_run - mnew);
      m_run = mnew;
      l_run *= sc;
#pragma unroll
      for (int r = 0; r < 16; ++r) { ot[0][r] *= sc; ot[1][r] *= sc; }
    }
    float p0[16], p1[16];
    float rsum = 0.f;
#pragma unroll
    for (int r = 0; r < 16; ++r) { p0[r] = EXP2(st[0][r] - m_run); rsum += p0[r]; }
#pragma unroll
    for (int r = 0; r < 16; ++r) { p1[r] = EXP2(st[1][r] - m_run); rsum += p1[r]; }
    l_run += rsum + __shfl_xor(rsum, 32, 64);

    uint32_t pa[4][4];
#pragma unroll
    for (int b = 0; b < 2; ++b) {
      const float* pp = b ? p1 : p0;
#pragma unroll
      for (int c = 0; c < 2; ++c) {
        uint32_t a0 = cvtpk_bf16(pp[8 * c + 0], pp[8 * c + 1]);
        uint32_t a1 = cvtpk_bf16(pp[8 * c + 2], pp[8 * c + 3]);
        uint32_t b0 = cvtpk_bf16(pp[8 * c + 4], pp[8 * c + 5]);
        uint32_t b1 = cvtpk_bf16(pp[8 * c + 6], pp[8 * c + 7]);
        perm32swap(a0, b0);
        perm32swap(a1, b1);
        pa[b * 2 + c][0] = a0; pa[b * 2 + c][1] = a1;
        pa[b * 2 + c][2] = b0; pa[b * 2 + c][3] = b1;
      }
    }

    __builtin_amdgcn_s_setprio(1);
#pragma unroll
    for (int ks = 0; ks < 4; ++ks) {
      bf16x8 pf = *(bf16x8*)&pa[ks][0];
#pragma unroll
      for (int db = 0; db < 2; ++db) {
        const int cb = (ks * 32 + hi * 16) ^ swz;
        bf16x8 vf = *(const bf16x8*)((const char*)&Vlds[cur][0] + (db * 32 + lq) * 128 + cb);
        ot[db] = MFMA32(vf, pf, ot[db]);
      }
    }
    __builtin_amdgcn_s_setprio(0);
    cur ^= 1;
  }

  const float linv = 1.f / l_run;
  float* orow = out + (rowbase + qrow) * 1024 + h * 64;
#pragma unroll
  for (int db = 0; db < 2; ++db)
#pragma unroll
    for (int m = 0; m < 4; ++m) {
      float4 v;
      v.x = ot[db][4 * m + 0] * linv;
      v.y = ot[db][4 * m + 1] * linv;
      v.z = ot[db][4 * m + 2] * linv;
      v.w = ot[db][4 * m + 3] * linv;
      *(float4*)(orow + db * 32 + 8 * m + 4 * hi) = v;
    }
}

// ---------------- residual + layernorm:  y = LN(xa + xb [+ xc]) * g + b ----------------
__global__ __launch_bounds__(256) void ln_kernel(const float* __restrict__ xa,
                                                 const float* __restrict__ xb,
                                                 const float* __restrict__ xc,
                                                 const float* __restrict__ g,
                                                 const float* __restrict__ b,
                                                 float* __restrict__ y32,
                                                 uint16_t* __restrict__ y16) {
  const int row = blockIdx.x;
  const int t = threadIdx.x;
  const int l = t & 63, w = t >> 6;
  float4 va = *((const float4*)(xa + (size_t)row * 1024) + t);
  float4 vb = *((const float4*)(xb + (size_t)row * 1024) + t);
  float x0 = va.x + vb.x, x1 = va.y + vb.y, x2 = va.z + vb.z, x3 = va.w + vb.w;
  if (xc) {
    float4 vc = *((const float4*)(xc + (size_t)row * 1024) + t);
    x0 += vc.x; x1 += vc.y; x2 += vc.z; x3 += vc.w;
  }
  float s = x0 + x1 + x2 + x3;
  float q = x0 * x0 + x1 * x1 + x2 * x2 + x3 * x3;
#pragma unroll
  for (int off = 1; off < 64; off <<= 1) {
    s += __shfl_xor(s, off, 64);
    q += __shfl_xor(q, off, 64);
  }
  __shared__ float red[8];
  if (l == 0) { red[w] = s; red[w + 4] = q; }
  __syncthreads();
  s = red[0] + red[1] + red[2] + red[3];
  q = red[4] + red[5] + red[6] + red[7];
  const float mu = s * (1.f / 1024.f);
  const float var = q * (1.f / 1024.f) - mu * mu;
  const float rstd = rsqrtf(var + 1e-5f);
  float4 vg = *((const float4*)g + t);
  float4 vbb = *((const float4*)b + t);
  float y0 = (x0 - mu) * rstd * vg.x + vbb.x;
  float y1 = (x1 - mu) * rstd * vg.y + vbb.y;
  float y2 = (x2 - mu) * rstd * vg.z + vbb.z;
  float y3 = (x3 - mu) * rstd * vg.w + vbb.w;
  *((float4*)(y32 + (size_t)row * 1024) + t) = make_float4(y0, y1, y2, y3);
  if (y16) {
    union { uint16_t u[4]; uint64_t v; } o;
    o.u[0] = f2bf(y0); o.u[1] = f2bf(y1); o.u[2] = f2bf(y2); o.u[3] = f2bf(y3);
    *((uint64_t*)(y16 + (size_t)row * 1024) + t) = o.v;
  }
}

extern "C" void kernel_launch(void* const* d_in, const int* in_sizes, int n_in,
                              void* d_out, int out_size, void* d_ws, size_t ws_size,
                              hipStream_t stream) {
  const float* embed = (const float*)d_in[0];
  const float* Wk = (const float*)d_in[1];
  const float* Wq = (const float*)d_in[2];
  const float* Wv = (const float*)d_in[3];
  const float* w1w = (const float*)d_in[4];
  const float* w1bias = (const float*)d_in[5];
  const float* w2w = (const float*)d_in[6];
  const float* w2bias = (const float*)d_in[7];
  const float* lng = (const float*)d_in[8];
  const float* lnb = (const float*)d_in[9];
  const float* ln2g = (const float*)d_in[10];
  const float* ln2b = (const float*)d_in[11];

  char* ws = (char*)d_ws;
  uint16_t* qkv  = (uint16_t*)(ws);                  // 25165824 ; reused as f32 FFN2 partial (16.8MB)
  uint16_t* xbf  = (uint16_t*)(ws + 25165824);       // 8388608
  uint16_t* wqkv = (uint16_t*)(ws + 33554432);       // 6291456
  uint16_t* w1b  = (uint16_t*)(ws + 39845888);       // 8388608
  uint16_t* w2b  = (uint16_t*)(ws + 48234496);       // 8388608
  float*    attf = (float*)(ws + 56623104);          // 16777216
  float*    yf   = (float*)(ws + 73400320);          // 16777216
  uint16_t* hid  = (uint16_t*)(ws + 90177536);       // 33554432 (FFN1 out)
  uint16_t* Vt   = (uint16_t*)(ws + 90177536);       // 8388608 (only live pre-FFN1)
  float*    part = (float*)qkv;                      // FFN2 split-K slice-1 partial

  // one fused cast: 15728640 elems / 4 per thread / 256 per block
  cast_all<<<dim3(15360), dim3(256), 0, stream>>>(embed, Wq, Wk, Wv, w1w, w2w,
                                                  xbf, wqkv, w1b, w2b);

  // QKV projection: [4096,1024] x [3072,1024]^T -> [4096,3072] bf16
  gemm_bt<0><<<dim3(32, 24), dim3(256), 0, stream>>>(xbf, wqkv, qkv, nullptr, nullptr,
                                                     4096, 3072, 1024, 1024);
  // V transpose
  transpose_v<<<dim3(32, 32), dim3(256), 0, stream>>>(qkv, Vt);
  // attention
  attn_kernel<<<dim3(16, 32), dim3(256), 0, stream>>>(qkv, Vt, attf);
  // residual + LN1 -> yf (f32), xbf (bf16)
  ln_kernel<<<dim3(4096), dim3(256), 0, stream>>>(attf, embed, nullptr, lng, lnb, yf, xbf);
  // FFN1: silu(y @ w1^T + b1) -> hid bf16
  gemm_bt<1><<<dim3(32, 32), dim3(256), 0, stream>>>(xbf, w1b, hid, nullptr, w1bias,
                                                     4096, 4096, 1024, 1024);
  // FFN2 split-K=2 (single dispatch, z = K-slice): slice0 -> attf (+bias), slice1 -> part
  gemm_bt<2><<<dim3(32, 8, 2), dim3(256), 0, stream>>>(hid, w2b, attf, part, w2bias,
                                                       4096, 1024, 2048, 4096);
  // residual + LN2 (attf + part + yf) -> d_out
  ln_kernel<<<dim3(4096), dim3(256), 0, stream>>>(attf, part, yf, ln2g, ln2b, (float*)d_out, nullptr);
}